// Round 1
// baseline (1404.359 us; speedup 1.0000x reference)
//
#include <hip/hip_runtime.h>
#include <hip/hip_bf16.h>

#define VOCAB 50000
#define NT    200
#define NTP   256   // padded topics (GEMM1 M)
#define EMB   512
#define BATCH 2048
#define KP    224   // padded K for GEMM2 (topics, 7*32)
#define TK    20

typedef __bf16 bf16x8 __attribute__((ext_vector_type(8)));
typedef float  f32x4  __attribute__((ext_vector_type(4)));

// ---- workspace layout (bytes) ----
#define OFF_EXPWT   0ull                 // [200][50000] f32  = 40,000,000
#define OFF_BETA    40000000ull          // [224][50000] bf16 = 22,400,000
#define OFF_THETAB  62400000ull          // [2048][224] bf16  =    917,504
#define OFF_TOPICA  63317504ull          // [256][512] bf16   =    262,144
#define OFF_ROWSUM  63579648ull          // [200] f32         =        800
#define OFF_STDR    63580448ull          // f32               =          4
#define OFF_TKV     63580464ull          // [200][20] f32
#define OFF_TKI     63596464ull          // [200][20] i32
#define OFF_TKSQ    63612464ull          // [200] f32
// total ~63.62 MB

// ---------------- theta = softmax(alpha) ----------------
__global__ __launch_bounds__(64) void k_theta(const float* __restrict__ alpha,
                                              float* __restrict__ theta_out,
                                              __bf16* __restrict__ theta_b) {
    int b = blockIdx.x;
    int ln = threadIdx.x;
    const float* row = alpha + (size_t)b * NT;
    float a0 = row[ln], a1 = row[ln + 64], a2 = row[ln + 128];
    float a3 = (ln < 8) ? row[ln + 192] : -1e30f;
    float m = fmaxf(fmaxf(a0, a1), fmaxf(a2, a3));
    #pragma unroll
    for (int off = 32; off; off >>= 1) m = fmaxf(m, __shfl_xor(m, off));
    float e0 = __expf(a0 - m), e1 = __expf(a1 - m), e2 = __expf(a2 - m);
    float e3 = (ln < 8) ? __expf(a3 - m) : 0.f;
    float s = e0 + e1 + e2 + e3;
    #pragma unroll
    for (int off = 32; off; off >>= 1) s += __shfl_xor(s, off);
    float inv = 1.f / s;
    float* o = theta_out + (size_t)b * NT;
    __bf16* ob = theta_b + (size_t)b * KP;
    o[ln]       = e0 * inv;  ob[ln]       = (__bf16)(e0 * inv);
    o[ln + 64]  = e1 * inv;  ob[ln + 64]  = (__bf16)(e1 * inv);
    o[ln + 128] = e2 * inv;  ob[ln + 128] = (__bf16)(e2 * inv);
    if (ln < 8)       { o[ln + 192] = e3 * inv; ob[ln + 192] = (__bf16)(e3 * inv); }
    else if (ln < 32) { ob[ln + 192] = (__bf16)0.f; }  // pad cols 200..223
}

// ---------------- topic_emb fp32 -> bf16, pad M to 256 ----------------
__global__ __launch_bounds__(256) void k_topic_cvt(const float* __restrict__ te,
                                                   __bf16* __restrict__ out) {
    int i = blockIdx.x * 256 + threadIdx.x;   // < 256*512
    int t = i >> 9, k = i & 511;
    out[i] = (t < NT) ? (__bf16)te[(size_t)t * EMB + k] : (__bf16)0.f;
}

// ---------------- GEMM1: expwt = exp(topicA @ wemb), rowsum ----------------
// block: all 256 (padded) topic rows x 64 vocab cols; 4 waves each own 64 rows.
__global__ __launch_bounds__(256) void k_gemm1(const float* __restrict__ wemb,
                                               const __bf16* __restrict__ Abf,
                                               float* __restrict__ expwt,
                                               float* __restrict__ rowsum) {
    __shared__ __align__(16) __bf16 lA[NTP * 40];  // [256][pitch 40 bf16 = 80B]
    __shared__ __align__(16) __bf16 lB[64 * 40];   // [64 cols][pitch 40]
    int tid = threadIdx.x;
    int v0 = blockIdx.x * 64;
    int w = tid >> 6, ln = tid & 63, quad = ln >> 4, c16 = ln & 15;

    f32x4 acc[4][4];
    #pragma unroll
    for (int mi = 0; mi < 4; ++mi)
        #pragma unroll
        for (int ni = 0; ni < 4; ++ni) acc[mi][ni] = (f32x4){0.f, 0.f, 0.f, 0.f};

    for (int ks = 0; ks < EMB / 32; ++ks) {
        int k0 = ks * 32;
        __syncthreads();
        { // stage A chunk [256][32] bf16 (row per thread, 4x uint4)
            const uint4* src = (const uint4*)(Abf + (size_t)tid * EMB + k0);
            uint4* dst = (uint4*)(&lA[tid * 40]);
            dst[0] = src[0]; dst[1] = src[1]; dst[2] = src[2]; dst[3] = src[3];
        }
        { // stage B chunk transposed [64 cols][32 k], fp32->bf16 on the fly
            int c = tid & 63, kg = tid >> 6;
            int v = v0 + c;
            bool ok = (v < VOCAB);
            #pragma unroll
            for (int it = 0; it < 8; ++it) {
                int k = kg * 8 + it;
                float val = ok ? wemb[(size_t)(k0 + k) * VOCAB + v] : 0.f;
                lB[c * 40 + k] = (__bf16)val;
            }
        }
        __syncthreads();
        bf16x8 aF[4], bF[4];
        #pragma unroll
        for (int mi = 0; mi < 4; ++mi)
            aF[mi] = *(const bf16x8*)(&lA[(w * 64 + mi * 16 + c16) * 40 + quad * 8]);
        #pragma unroll
        for (int ni = 0; ni < 4; ++ni)
            bF[ni] = *(const bf16x8*)(&lB[(ni * 16 + c16) * 40 + quad * 8]);
        #pragma unroll
        for (int mi = 0; mi < 4; ++mi)
            #pragma unroll
            for (int ni = 0; ni < 4; ++ni)
                acc[mi][ni] = __builtin_amdgcn_mfma_f32_16x16x32_bf16(aF[mi], bF[ni], acc[mi][ni], 0, 0, 0);
    }

    // epilogue: exp, store, rowsum
    #pragma unroll
    for (int mi = 0; mi < 4; ++mi) {
        #pragma unroll
        for (int r = 0; r < 4; ++r) {
            int tt = w * 64 + mi * 16 + quad * 4 + r;   // uniform within 16-lane group
            float rs = 0.f;
            if (tt < NT) {
                #pragma unroll
                for (int ni = 0; ni < 4; ++ni) {
                    int v = v0 + ni * 16 + c16;
                    if (v < VOCAB) {
                        float e = __expf(acc[mi][ni][r]);
                        expwt[(size_t)tt * VOCAB + v] = e;
                        rs += e;
                    }
                }
            }
            #pragma unroll
            for (int off = 1; off < 16; off <<= 1) rs += __shfl_xor(rs, off, 16);
            if (tt < NT && c16 == 0) atomicAdd(&rowsum[tt], rs);
        }
    }
}

// ---------------- beta_bf16 = expwt / rowsum (K rows padded to 224) ----------------
__global__ __launch_bounds__(256) void k_norm(const float* __restrict__ expwt,
                                              const float* __restrict__ rowsum,
                                              __bf16* __restrict__ beta) {
    int t = blockIdx.y;
    int v = blockIdx.x * 256 + threadIdx.x;
    if (v >= VOCAB) return;
    float out = 0.f;
    if (t < NT) out = expwt[(size_t)t * VOCAB + v] * (1.f / rowsum[t]);
    beta[(size_t)t * VOCAB + v] = (__bf16)out;
}

// ---------------- GEMM2: C = theta @ beta, fused Re = -sum log(C)*bow ----------------
// block tile: 128 batch rows x 128 vocab cols; wave w owns rows 32w..32w+31.
__global__ __launch_bounds__(256) void k_gemm2(const __bf16* __restrict__ thetab,
                                               const __bf16* __restrict__ beta,
                                               const float* __restrict__ bow,
                                               float* __restrict__ Re) {
    __shared__ __align__(16) __bf16 lA[128 * 40];
    __shared__ __align__(16) __bf16 lB[128 * 40];
    int tid = threadIdx.x;
    int m0 = blockIdx.x * 128;
    int v0 = blockIdx.y * 128;
    int w = tid >> 6, ln = tid & 63, quad = ln >> 4, c16 = ln & 15;

    f32x4 acc[2][8];
    #pragma unroll
    for (int mi = 0; mi < 2; ++mi)
        #pragma unroll
        for (int ni = 0; ni < 8; ++ni) acc[mi][ni] = (f32x4){0.f, 0.f, 0.f, 0.f};

    for (int ks = 0; ks < KP / 32; ++ks) {
        int k0 = ks * 32;
        __syncthreads();
        { // stage A [128 rows][32 k]: 512 uint4, 2 per thread
            #pragma unroll
            for (int i = 0; i < 2; ++i) {
                int u = tid * 2 + i;
                int row = u >> 2, seg = u & 3;
                *(uint4*)(&lA[row * 40 + seg * 8]) =
                    *(const uint4*)(thetab + (size_t)(m0 + row) * KP + k0 + seg * 8);
            }
        }
        { // stage B transposed [128 cols][32 k]
            int c = tid & 127, kg = tid >> 7;
            int v = v0 + c;
            bool ok = (v < VOCAB);
            #pragma unroll
            for (int it = 0; it < 16; ++it) {
                int k = kg * 16 + it;
                __bf16 val = ok ? beta[(size_t)(k0 + k) * VOCAB + v] : (__bf16)0.f;
                lB[c * 40 + k] = val;
            }
        }
        __syncthreads();
        bf16x8 aF[2], bF[8];
        #pragma unroll
        for (int mi = 0; mi < 2; ++mi)
            aF[mi] = *(const bf16x8*)(&lA[(w * 32 + mi * 16 + c16) * 40 + quad * 8]);
        #pragma unroll
        for (int ni = 0; ni < 8; ++ni)
            bF[ni] = *(const bf16x8*)(&lB[(ni * 16 + c16) * 40 + quad * 8]);
        #pragma unroll
        for (int mi = 0; mi < 2; ++mi)
            #pragma unroll
            for (int ni = 0; ni < 8; ++ni)
                acc[mi][ni] = __builtin_amdgcn_mfma_f32_16x16x32_bf16(aF[mi], bF[ni], acc[mi][ni], 0, 0, 0);
    }

    // fused epilogue: per-row partial of log(C)*bow, reduce over 16 cols, atomic
    #pragma unroll
    for (int mi = 0; mi < 2; ++mi) {
        #pragma unroll
        for (int r = 0; r < 4; ++r) {
            int b = m0 + w * 32 + mi * 16 + quad * 4 + r;
            float s = 0.f;
            #pragma unroll
            for (int ni = 0; ni < 8; ++ni) {
                int v = v0 + ni * 16 + c16;
                if (v < VOCAB)
                    s += __logf(acc[mi][ni][r]) * bow[(size_t)b * VOCAB + v];
            }
            #pragma unroll
            for (int off = 1; off < 16; off <<= 1) s += __shfl_xor(s, off, 16);
            if (c16 == 0) atomicAdd(&Re[b], -s);
        }
    }
}

// ---------------- per-topic top-20 of expwt (order == order of beta) ----------------
__global__ __launch_bounds__(256) void k_topk(const float* __restrict__ expwt,
                                              float* __restrict__ tkv,
                                              int* __restrict__ tki,
                                              float* __restrict__ tksq) {
    __shared__ float lv[256 * TK];
    __shared__ int   li[256 * TK];
    __shared__ int   head[256];
    __shared__ float redv[256];
    __shared__ int   redi[256];
    __shared__ float selv[TK];
    __shared__ int   seli[TK];
    int t = blockIdx.x, tid = threadIdx.x;
    const float* row = expwt + (size_t)t * VOCAB;

    float tv[TK]; int ti[TK];
    #pragma unroll
    for (int i = 0; i < TK; ++i) { tv[i] = -1e30f; ti[i] = 0; }

    for (int v = tid; v < VOCAB; v += 256) {
        float val = row[v];
        if (val > tv[TK - 1]) {
            #pragma unroll
            for (int i = TK - 1; i >= 1; --i) {
                bool sh  = val > tv[i - 1];
                bool put = val > tv[i];
                float nv = sh ? tv[i - 1] : (put ? val : tv[i]);
                int  nix = sh ? ti[i - 1] : (put ? v   : ti[i]);
                tv[i] = nv; ti[i] = nix;
            }
            if (val > tv[0]) { tv[0] = val; ti[0] = v; }
        }
    }
    #pragma unroll
    for (int i = 0; i < TK; ++i) { lv[tid * TK + i] = tv[i]; li[tid * TK + i] = ti[i]; }
    head[tid] = 0;
    __syncthreads();

    for (int sel = 0; sel < TK; ++sel) {
        int h = head[tid];
        redv[tid] = (h < TK) ? lv[tid * TK + h] : -1e30f;
        redi[tid] = tid;
        __syncthreads();
        for (int s2 = 128; s2 > 0; s2 >>= 1) {
            if (tid < s2) {
                if (redv[tid + s2] > redv[tid]) {
                    redv[tid] = redv[tid + s2]; redi[tid] = redi[tid + s2];
                }
            }
            __syncthreads();
        }
        if (tid == 0) {
            int wt = redi[0];
            int hh = head[wt];
            selv[sel] = lv[wt * TK + hh];
            seli[sel] = li[wt * TK + hh];
            head[wt] = hh + 1;
        }
        __syncthreads();
    }

    if (tid == 0) {
        float sum = 0.f;
        #pragma unroll
        for (int i = 0; i < TK; ++i) sum += selv[i];
        float inv = 1.f / sum, sq = 0.f;
        #pragma unroll
        for (int i = 0; i < TK; ++i) {
            float nv = selv[i] * inv;
            tkv[t * TK + i] = nv;
            tki[t * TK + i] = seli[i];
            sq += nv * nv;
        }
        tksq[t] = sq;
    }
}

// ---------------- STDR pairs: sum 0.5*||b_i - b_j||^2 over sparse rows ----------------
__global__ __launch_bounds__(256) void k_pairs(const float* __restrict__ tkv,
                                               const int* __restrict__ tki,
                                               const float* __restrict__ tksq,
                                               float* __restrict__ stdr) {
    int p = blockIdx.x * 256 + threadIdx.x;
    float contrib = 0.f;
    if (p < NT * NT) {
        int i = p / NT, j = p % NT;
        float vi[TK], vj[TK]; int ii[TK], ij[TK];
        #pragma unroll
        for (int a = 0; a < TK; ++a) { vi[a] = tkv[i * TK + a]; ii[a] = tki[i * TK + a]; }
        #pragma unroll
        for (int a = 0; a < TK; ++a) { vj[a] = tkv[j * TK + a]; ij[a] = tki[j * TK + a]; }
        float g = 0.f;
        for (int a = 0; a < TK; ++a) {
            #pragma unroll
            for (int b = 0; b < TK; ++b)
                if (ii[a] == ij[b]) g += vi[a] * vj[b];
        }
        float d2 = fmaxf(tksq[i] + tksq[j] - 2.f * g, 0.f);
        contrib = 0.5f * d2;
    }
    __shared__ float red[256];
    red[threadIdx.x] = contrib;
    __syncthreads();
    for (int s = 128; s; s >>= 1) {
        if (threadIdx.x < s) red[threadIdx.x] += red[threadIdx.x + s];
        __syncthreads();
    }
    if (threadIdx.x == 0) atomicAdd(stdr, red[0]);
}

__global__ void k_final(const float* __restrict__ stdr, float* __restrict__ out) {
    out[0] = stdr[0] * (1.f / (float)(NT * NT));
}

extern "C" void kernel_launch(void* const* d_in, const int* in_sizes, int n_in,
                              void* d_out, int out_size, void* d_ws, size_t ws_size,
                              hipStream_t stream) {
    const float* alpha = (const float*)d_in[0];
    const float* bow   = (const float*)d_in[1];
    const float* temb  = (const float*)d_in[2];
    const float* wemb  = (const float*)d_in[3];
    float* out = (float*)d_out;
    char* ws = (char*)d_ws;

    float*  expwt  = (float*)(ws + OFF_EXPWT);
    __bf16* beta   = (__bf16*)(ws + OFF_BETA);
    __bf16* thetab = (__bf16*)(ws + OFF_THETAB);
    __bf16* topA   = (__bf16*)(ws + OFF_TOPICA);
    float*  rowsum = (float*)(ws + OFF_ROWSUM);
    float*  stdr   = (float*)(ws + OFF_STDR);
    float*  tkv    = (float*)(ws + OFF_TKV);
    int*    tki    = (int*)(ws + OFF_TKI);
    float*  tksq   = (float*)(ws + OFF_TKSQ);

    float* Re        = out;              // [2048]
    float* stdr_out  = out + BATCH;      // [1]
    float* theta_out = out + BATCH + 1;  // [2048*200]

    hipMemsetAsync(Re, 0, BATCH * sizeof(float), stream);
    hipMemsetAsync(ws + OFF_ROWSUM, 0, 804, stream);   // rowsum + stdr accumulator

    k_theta<<<BATCH, 64, 0, stream>>>(alpha, theta_out, thetab);
    k_topic_cvt<<<512, 256, 0, stream>>>(temb, topA);
    k_gemm1<<<(VOCAB + 63) / 64, 256, 0, stream>>>(wemb, topA, expwt, rowsum);
    k_norm<<<dim3((VOCAB + 255) / 256, KP), 256, 0, stream>>>(expwt, rowsum, beta);
    k_gemm2<<<dim3(BATCH / 128, (VOCAB + 127) / 128), 256, 0, stream>>>(thetab, beta, bow, Re);
    k_topk<<<NT, 256, 0, stream>>>(expwt, tkv, tki, tksq);
    k_pairs<<<(NT * NT + 255) / 256, 256, 0, stream>>>(tkv, tki, tksq, stdr);
    k_final<<<1, 1, 0, stream>>>(stdr, stdr_out);
}